// Round 1
// 3218.916 us; speedup vs baseline: 2.9951x; 2.9951x over previous
//
#include <hip/hip_runtime.h>
#include <math.h>
#include <stdint.h>

#define HIDN 512
#define H3 1536
#define BSZN 4096
#define CNUM 4
#define NHEAD 8
#define LNUM 4
#define OUTN 32000
#define KS16 16            // K/32 for K=512
#define BIGC (1 << 30)

typedef unsigned short u16;
typedef __attribute__((ext_vector_type(4))) float f32x4;
typedef __attribute__((ext_vector_type(4))) unsigned int u32x4;

// ---------------------------------------------------------------
// split fp32 -> (hi, lo) bf16 pair, both RNE.  x ~= hi + lo, rel err ~2^-17.
__device__ __forceinline__ void split1(float x, unsigned& h, unsigned& l) {
    unsigned u = __float_as_uint(x);
    unsigned hr = (u + 0x7fffu + ((u >> 16) & 1u)) >> 16;
    float hf = __uint_as_float(hr << 16);
    float r = x - hf;
    unsigned v = __float_as_uint(r);
    l = ((v + 0x7fffu + ((v >> 16) & 1u)) >> 16) & 0xffffu;
    h = hr & 0xffffu;
}

// D += A*B via inline asm (avoids builtin vector-type ambiguity).
__device__ __forceinline__ void mfma16(f32x4& c, u32x4 a, u32x4 b) {
    asm volatile("v_mfma_f32_16x16x32_bf16 %0, %1, %2, %0"
                 : "+v"(c) : "v"(a), "v"(b));
}

// async global->LDS, 16B per lane.  LDS dest = uniform base + lane*16.
__device__ __forceinline__ void async16(const void* g, void* l) {
    __builtin_amdgcn_global_load_lds(
        (__attribute__((address_space(1))) unsigned int*)g,
        (__attribute__((address_space(3))) unsigned int*)l, 16, 0, 0);
}

// ---------------------------------------------------------------
// Convert fp32 (R,512) row-major into fragment-tiled bf16 hi/lo planes:
//   tiled[rt][ks][lane][e] = X[rt*16 + (lane&15)][ks*32 + (lane>>4)*8 + e]
// One thread handles 8 consecutive k of one row (one 16B tile slot).
// Optional ids: X[r][k] += ids[r / rows_per_c][k].
__global__ __launch_bounds__(256) void cvt_split_k(
    const float* __restrict__ X, u16* __restrict__ hi, u16* __restrict__ lo,
    const float* __restrict__ ids, int rows_per_c, int total)
{
    int s = blockIdx.x * 256 + threadIdx.x;
    if (s >= total) return;
    int r = s >> 6, li = s & 63;
    const float* xp = X + ((long)r << 9) + (li << 3);
    f32x4 x0 = *(const f32x4*)xp;
    f32x4 x1 = *(const f32x4*)(xp + 4);
    if (ids) {
        const float* ip = ids + ((long)(r / rows_per_c) << 9) + (li << 3);
        f32x4 i0 = *(const f32x4*)ip;
        f32x4 i1 = *(const f32x4*)(ip + 4);
        x0 += i0; x1 += i1;
    }
    float xs[8];
    xs[0] = x0[0]; xs[1] = x0[1]; xs[2] = x0[2]; xs[3] = x0[3];
    xs[4] = x1[0]; xs[5] = x1[1]; xs[6] = x1[2]; xs[7] = x1[3];
    unsigned hp[4], lq[4];
    #pragma unroll
    for (int j = 0; j < 4; ++j) {
        unsigned h0, l0, h1, l1;
        split1(xs[2 * j], h0, l0);
        split1(xs[2 * j + 1], h1, l1);
        hp[j] = h0 | (h1 << 16);
        lq[j] = l0 | (l1 << 16);
    }
    long d = (((long)(r >> 4) * KS16 + (li >> 2)) * 64 +
              ((r & 15) | ((li & 3) << 4))) * 8;
    *(u32x4*)(hi + d) = (u32x4){hp[0], hp[1], hp[2], hp[3]};
    *(u32x4*)(lo + d) = (u32x4){lq[0], lq[1], lq[2], lq[3]};
}

// ---------------------------------------------------------------
// Split-bf16 MFMA GEMM.  C[m][n] (+)= sum_k A[m][k]*B[n][k] + bias[c][n]
// A,B pre-converted fragment-tiled hi/lo (see cvt_split_k).  K=512 fixed.
// 128x128 tile, 4 waves, 64x64/wave (4x4 frags of 16x16), 3 MFMA per frag pair.
__global__ __launch_bounds__(256) void gemm_mfma(
    const u16* __restrict__ Ahi, const u16* __restrict__ Alo,
    const u16* __restrict__ Bhi, const u16* __restrict__ Blo,
    const float* __restrict__ bias, float* __restrict__ C,
    int ldc, long sBc, long sBias, int rows_per_c, int accum)
{
    __shared__ u16 lds[4 * 8 * 64 * 8];   // 32 KB: plane(Ahi,Alo,Bhi,Blo) x blk x lane x 8
    const int tid = threadIdx.x;
    const int w = tid >> 6, lane = tid & 63;
    const int row0 = blockIdx.y << 7;
    const int col0 = blockIdx.x << 7;
    const int c = row0 / rows_per_c;
    const int wr = w >> 1, wc = w & 1;

    const u16* gp[4];
    gp[0] = Ahi; gp[1] = Alo;
    gp[2] = Bhi + (long)c * sBc;
    gp[3] = Blo + (long)c * sBc;
    long tb[4];
    tb[0] = tb[1] = (long)(row0 >> 4);
    tb[2] = tb[3] = (long)(col0 >> 4);

    f32x4 acc[4][4];
    #pragma unroll
    for (int m = 0; m < 4; ++m)
        #pragma unroll
        for (int n = 0; n < 4; ++n) acc[m][n] = (f32x4){0.f, 0.f, 0.f, 0.f};

    for (int ks = 0; ks < KS16; ++ks) {
        // stage 32 chunks of 1KB (each: 64 lanes x 16B), 8 per wave
        #pragma unroll
        for (int i = 0; i < 8; ++i) {
            const int q = w + (i << 2);
            const int p = q >> 3;          // compile-time per i (0,0,1,1,2,2,3,3)
            const int blk = q & 7;
            const u16* src = gp[p] + (((tb[p] + blk) * KS16 + ks) << 9) + (lane << 3);
            u16* dst = lds + (((p << 3) + blk) << 9);
            async16(src, dst);
        }
        __syncthreads();   // drains vmcnt(0) before barrier

        u32x4 bh[4], bl[4];
        #pragma unroll
        for (int n = 0; n < 4; ++n) {
            bh[n] = *(const u32x4*)(lds + ((16 + (wc << 2) + n) << 9) + (lane << 3));
            bl[n] = *(const u32x4*)(lds + ((24 + (wc << 2) + n) << 9) + (lane << 3));
        }
        #pragma unroll
        for (int m = 0; m < 4; ++m) {
            u32x4 ah = *(const u32x4*)(lds + ((( wr << 2) + m) << 9) + (lane << 3));
            u32x4 al = *(const u32x4*)(lds + ((8 + (wr << 2) + m) << 9) + (lane << 3));
            #pragma unroll
            for (int n = 0; n < 4; ++n) mfma16(acc[m][n], ah, bh[n]);
            #pragma unroll
            for (int n = 0; n < 4; ++n) mfma16(acc[m][n], ah, bl[n]);
            #pragma unroll
            for (int n = 0; n < 4; ++n) mfma16(acc[m][n], al, bh[n]);
        }
        __syncthreads();
    }

    // epilogue: D row = (lane>>4)*4 + reg, col = lane&15  [verified C/D layout]
    const int lane15 = lane & 15, lgrp = lane >> 4;
    const long colb = col0 + (wc << 6) + lane15;
    float bv[4];
    #pragma unroll
    for (int n = 0; n < 4; ++n) bv[n] = bias[(long)c * sBias + colb + (n << 4)];
    #pragma unroll
    for (int m = 0; m < 4; ++m) {
        #pragma unroll
        for (int r = 0; r < 4; ++r) {
            const long row = row0 + (wr << 6) + (m << 4) + (lgrp << 2) + r;
            const long ro = row * (long)ldc + colb;
            #pragma unroll
            for (int n = 0; n < 4; ++n) {
                float v = acc[m][n][r] + bv[n];
                if (accum) C[ro + (n << 4)] += v;
                else       C[ro + (n << 4)] = v;
            }
        }
    }
}

// =====================================================================
// fp32 fallback GEMM (previous round's kernel) — used only if ws too small.
__global__ __launch_bounds__(256) void gemm_bt(
    const float* __restrict__ A, const float* __restrict__ B,
    const float* __restrict__ bias, const float* __restrict__ ids,
    float* __restrict__ C, int M, int N, int K, int ldc,
    long sBc, long sBias, long sIds, int rows_per_c, int accum)
{
    __shared__ float As[16][65];
    __shared__ float Bs[16][65];
    int tid = threadIdx.x;
    int tx = tid & 15, ty = tid >> 4;
    int row0 = blockIdx.y * 64, col0 = blockIdx.x * 64;
    int c = row0 / rows_per_c;
    const float* Bc    = B + (long)c * sBc;
    const float* biasc = bias + (long)c * sBias;
    const float* idsc  = ids ? (ids + (long)c * sIds) : nullptr;

    int lm = tid >> 2;
    int lk = (tid & 3) << 2;
    const float* Aptr = A  + (long)(row0 + lm) * K + lk;
    const float* Bptr = Bc + (long)(col0 + lm) * K + lk;

    float acc[4][4] = {};
    for (int k0 = 0; k0 < K; k0 += 16) {
        float4 av = *(const float4*)(Aptr + k0);
        if (idsc) {
            float4 iv = *(const float4*)(idsc + k0 + lk);
            av.x += iv.x; av.y += iv.y; av.z += iv.z; av.w += iv.w;
        }
        As[lk+0][lm] = av.x; As[lk+1][lm] = av.y;
        As[lk+2][lm] = av.z; As[lk+3][lm] = av.w;
        float4 bv = *(const float4*)(Bptr + k0);
        Bs[lk+0][lm] = bv.x; Bs[lk+1][lm] = bv.y;
        Bs[lk+2][lm] = bv.z; Bs[lk+3][lm] = bv.w;
        __syncthreads();
        #pragma unroll
        for (int kk = 0; kk < 16; ++kk) {
            float a[4], b[4];
            #pragma unroll
            for (int i = 0; i < 4; ++i) a[i] = As[kk][ty*4+i];
            #pragma unroll
            for (int j = 0; j < 4; ++j) b[j] = Bs[kk][tx*4+j];
            #pragma unroll
            for (int i = 0; i < 4; ++i)
                #pragma unroll
                for (int j = 0; j < 4; ++j)
                    acc[i][j] += a[i] * b[j];
        }
        __syncthreads();
    }
    #pragma unroll
    for (int i = 0; i < 4; ++i) {
        int r = row0 + ty*4 + i;
        #pragma unroll
        for (int j = 0; j < 4; ++j) {
            int cl = col0 + tx*4 + j;
            float v = acc[i][j] + biasc[cl];
            long off = (long)r * ldc + cl;
            if (accum) C[off] += v; else C[off] = v;
        }
    }
}

// ---------------- embedding lookup
__global__ void embed_k(const int* __restrict__ tokens, const float* __restrict__ emb,
                        float* __restrict__ x, int total)
{
    int idx = blockIdx.x * blockDim.x + threadIdx.x;
    if (idx >= total) return;
    int b = idx >> 9, e = idx & 511;
    x[idx] = emb[(long)tokens[b] * HIDN + e];
}

// ---------------- fill gx rows with per-c bias
__global__ void fill_bias_k(float* __restrict__ dst, const float* __restrict__ bias,
                            int N, long sBias, int rows_per_c, int total)
{
    int idx = blockIdx.x * blockDim.x + threadIdx.x;
    if (idx >= total) return;
    int r = idx / N, col = idx % N;
    int c = r / rows_per_c;
    dst[idx] = bias[(long)c * sBias + col];
}

// ---------------- GRU gates
__global__ void gru_gates_k(const float* __restrict__ S, const float* __restrict__ Hn,
                            const float* __restrict__ hp, float* __restrict__ hout,
                            int total)
{
    int idx = blockIdx.x * blockDim.x + threadIdx.x;
    if (idx >= total) return;
    int row = idx >> 9, hcol = idx & 511;
    long base = (long)row * H3;
    float rr = S[base + hcol];
    float zz = S[base + HIDN + hcol];
    float xn = S[base + 2*HIDN + hcol];
    float hn = Hn[idx];
    float r = 1.f / (1.f + expf(-rr));
    float z = 1.f / (1.f + expf(-zz));
    float n = tanhf(xn + r * hn);
    hout[idx] = (1.f - z) * n + z * hp[idx];
}

// ---------------- attention over C=4
__global__ __launch_bounds__(256) void attn_k(const float* __restrict__ qkbuf,
                                              const float* __restrict__ vbuf,
                                              float* __restrict__ obuf)
{
    int wave = (blockIdx.x * blockDim.x + threadIdx.x) >> 6;
    int lane = threadIdx.x & 63;
    int b = wave >> 3, n = wave & 7;
    float qv[4], kv[4], vv[4];
    #pragma unroll
    for (int c = 0; c < 4; ++c) {
        long rqk = (long)(c * BSZN + b) * 1024 + n * 64 + lane;
        qv[c] = qkbuf[rqk];
        kv[c] = qkbuf[rqk + 512];
        vv[c] = vbuf[(long)(c * BSZN + b) * 512 + n * 64 + lane];
    }
    float s[4][4];
    #pragma unroll
    for (int qi = 0; qi < 4; ++qi)
        #pragma unroll
        for (int ki = 0; ki < 4; ++ki) {
            float p = qv[qi] * kv[ki];
            #pragma unroll
            for (int off = 32; off; off >>= 1) p += __shfl_xor(p, off);
            s[qi][ki] = p * 0.125f;
        }
    #pragma unroll
    for (int qi = 0; qi < 4; ++qi) {
        float mx = fmaxf(fmaxf(s[qi][0], s[qi][1]), fmaxf(s[qi][2], s[qi][3]));
        float e0 = expf(s[qi][0]-mx), e1 = expf(s[qi][1]-mx);
        float e2 = expf(s[qi][2]-mx), e3 = expf(s[qi][3]-mx);
        float inv = 1.f / (e0 + e1 + e2 + e3);
        float ov = (e0*vv[0] + e1*vv[1] + e2*vv[2] + e3*vv[3]) * inv;
        obuf[(long)(qi * BSZN + b) * 512 + n * 64 + lane] = ov;
    }
}

// ---------------- fused LayerNorm + gate + residual mix
__global__ __launch_bounds__(256) void ln_gate_k(
    const float* __restrict__ msg_pre, const float* __restrict__ hln,
    const float* __restrict__ lng, const float* __restrict__ lnb,
    const float* __restrict__ gw, const float* __restrict__ gb,
    float* __restrict__ hn_out, int rows)
{
    int wave = (blockIdx.x * blockDim.x + threadIdx.x) >> 6;
    int lane = threadIdx.x & 63;
    if (wave >= rows) return;
    const float* mrow = msg_pre + (long)wave * 512;
    float m[8];
    float sum = 0.f;
    #pragma unroll
    for (int i = 0; i < 8; ++i) { m[i] = mrow[lane + i*64]; sum += m[i]; }
    #pragma unroll
    for (int off = 32; off; off >>= 1) sum += __shfl_xor(sum, off);
    float mu = sum * (1.f / 512.f);
    float sq = 0.f;
    #pragma unroll
    for (int i = 0; i < 8; ++i) { float d = m[i] - mu; sq += d * d; }
    #pragma unroll
    for (int off = 32; off; off >>= 1) sq += __shfl_xor(sq, off);
    float rstd = rsqrtf(sq * (1.f / 512.f) + 1e-5f);

    const float* hrow = hln + (long)wave * 512;
    float msg[8], h[8];
    float gdot = 0.f;
    #pragma unroll
    for (int i = 0; i < 8; ++i) {
        int col = lane + i * 64;
        msg[i] = (m[i] - mu) * rstd * lng[col] + lnb[col];
        h[i] = hrow[col];
        gdot += h[i] * gw[col] + msg[i] * gw[512 + col];
    }
    #pragma unroll
    for (int off = 32; off; off >>= 1) gdot += __shfl_xor(gdot, off);
    float g = 1.f / (1.f + expf(-(gdot + gb[0])));
    float* orow = hn_out + (long)wave * 512;
    #pragma unroll
    for (int i = 0; i < 8; ++i)
        orow[lane + i * 64] = (1.f - g) * h[i] + g * msg[i];
}

// =====================================================================
extern "C" void kernel_launch(void* const* d_in, const int* in_sizes, int n_in,
                              void* d_out, int out_size, void* d_ws, size_t ws_size,
                              hipStream_t stream)
{
    const int*   tokens   = (const int*)  d_in[0];
    const float* h_in     = (const float*)d_in[1];
    const float* emb      = (const float*)d_in[2];
    const float* W_ih_00  = (const float*)d_in[3];
    const float* W_hh_00  = (const float*)d_in[4];
    const float* b_ih_00  = (const float*)d_in[5];
    const float* b_hh_00  = (const float*)d_in[6];
    // d_in[7] = W_ih_0r: multiplied by zeros -> unused
    const float* W_hh_0r  = (const float*)d_in[8];
    const float* b_ih_0r  = (const float*)d_in[9];
    const float* b_hh_0r  = (const float*)d_in[10];
    const float* W_ih     = (const float*)d_in[11];
    const float* W_hh     = (const float*)d_in[12];
    const float* b_ih     = (const float*)d_in[13];
    const float* b_hh     = (const float*)d_in[14];
    const float* ids      = (const float*)d_in[15];
    const float* in_w     = (const float*)d_in[16];
    const float* in_b     = (const float*)d_in[17];
    const float* out_w    = (const float*)d_in[18];
    const float* out_b    = (const float*)d_in[19];
    const float* ln_g     = (const float*)d_in[20];
    const float* ln_b     = (const float*)d_in[21];
    const float* gate_w   = (const float*)d_in[22];
    const float* gate_b   = (const float*)d_in[23];
    const float* head_w   = (const float*)d_in[24];
    const float* head_b   = (const float*)d_in[25];

    float* y  = (float*)d_out;
    float* hn = y + (long)BSZN * OUTN;

    const long ROWS  = (long)CNUM * BSZN;     // 16384
    const long LAYER = ROWS * HIDN;
    const long S_F   = ROWS * H3;

    float* S    = (float*)d_ws;
    float* Hn   = S   + S_F;
    float* hln  = Hn  + LAYER;
    float* xbuf = hln + LAYER;
    float* qk   = S;
    float* obuf = S + ROWS * 1024;
    float* mpre = S;
    float* vbuf = Hn;

    const long WROWS = 1536 + 1536 + 4608 + 18432 + 18432 + 6144 + 2048 + 32000; // 84736
    size_t need = (size_t)(S_F + 2 * LAYER + (long)BSZN * HIDN) * 4
                + (size_t)(WROWS + 2 * ROWS) * 2048;

    if (ws_size < need) {
        // ---------- fallback: previous fp32 path ----------
        auto gemo = [&](const float* A, const float* B, const float* bias,
                        const float* idsp, float* C, int M, int N, int K, int ldc,
                        long sBc, long sBias, long sIds, int rpc, int accum) {
            dim3 grid(N / 64, M / 64);
            hipLaunchKernelGGL(gemm_bt, grid, dim3(256), 0, stream,
                               A, B, bias, idsp, C, M, N, K, ldc,
                               sBc, sBias, sIds, rpc, accum);
        };
        hipLaunchKernelGGL(embed_k, dim3((BSZN * HIDN) / 256), dim3(256), 0, stream,
                           tokens, emb, xbuf, BSZN * HIDN);
        for (int l = 0; l < LNUM; ++l) {
            const float* hl  = h_in + (long)l * LAYER;
            const float* xin = (l == 0) ? nullptr : (hn + (long)(l - 1) * LAYER);
            if (l == 0) {
                gemo(xbuf, W_ih_00, b_ih_00, nullptr, S, BSZN, H3, HIDN, H3, 0, 0, 0, BIGC, 0);
                int total = (CNUM - 1) * BSZN * H3;
                hipLaunchKernelGGL(fill_bias_k, dim3((total + 255) / 256), dim3(256), 0, stream,
                                   S + (long)BSZN * H3, b_ih_0r, H3, (long)H3, BSZN, total);
                gemo(hl, W_hh_00, b_hh_00, nullptr, S, BSZN, 1024, HIDN, H3, 0, 0, 0, BIGC, 1);
                gemo(hl, W_hh_00 + 1024 * HIDN, b_hh_00 + 1024, nullptr, Hn,
                     BSZN, HIDN, HIDN, HIDN, 0, 0, 0, BIGC, 0);
                gemo(hl + (long)BSZN * HIDN, W_hh_0r, b_hh_0r, nullptr,
                     S + (long)BSZN * H3, (CNUM - 1) * BSZN, 1024, HIDN, H3,
                     (long)H3 * HIDN, (long)H3, 0, BSZN, 1);
                gemo(hl + (long)BSZN * HIDN, W_hh_0r + 1024 * HIDN, b_hh_0r + 1024, nullptr,
                     Hn + (long)BSZN * HIDN, (CNUM - 1) * BSZN, HIDN, HIDN, HIDN,
                     (long)H3 * HIDN, (long)H3, 0, BSZN, 0);
            } else {
                const float* Wi = W_ih + (long)(l - 1) * CNUM * H3 * HIDN;
                const float* Wh = W_hh + (long)(l - 1) * CNUM * H3 * HIDN;
                const float* bi = b_ih + (long)(l - 1) * CNUM * H3;
                const float* bh = b_hh + (long)(l - 1) * CNUM * H3;
                gemo(xin, Wi, bi, nullptr, S, ROWS, H3, HIDN, H3,
                     (long)H3 * HIDN, (long)H3, 0, BSZN, 0);
                gemo(hl, Wh, bh, nullptr, S, ROWS, 1024, HIDN, H3,
                     (long)H3 * HIDN, (long)H3, 0, BSZN, 1);
                gemo(hl, Wh + 1024 * HIDN, bh + 1024, nullptr, Hn, ROWS, HIDN, HIDN, HIDN,
                     (long)H3 * HIDN, (long)H3, 0, BSZN, 0);
            }
            hipLaunchKernelGGL(gru_gates_k, dim3((ROWS * HIDN) / 256), dim3(256), 0, stream,
                               S, Hn, hl, hln, (int)(ROWS * HIDN));
            const float* Wi_l = in_w + (long)l * H3 * HIDN;
            const float* bi_l = in_b + (long)l * H3;
            gemo(hln, Wi_l, bi_l, ids + (long)l * CNUM * HIDN, qk,
                 ROWS, 1024, HIDN, 1024, 0, 0, (long)HIDN, BSZN, 0);
            gemo(hln, Wi_l + 1024 * HIDN, bi_l + 1024, nullptr, vbuf,
                 ROWS, HIDN, HIDN, HIDN, 0, 0, 0, BIGC, 0);
            hipLaunchKernelGGL(attn_k, dim3((BSZN * NHEAD * 64) / 256), dim3(256), 0, stream,
                               qk, vbuf, obuf);
            gemo(obuf, out_w + (long)l * HIDN * HIDN, out_b + (long)l * HIDN, nullptr,
                 mpre, ROWS, HIDN, HIDN, HIDN, 0, 0, 0, BIGC, 0);
            hipLaunchKernelGGL(ln_gate_k, dim3((ROWS * 64) / 256), dim3(256), 0, stream,
                               mpre, hln, ln_g + (long)l * HIDN, ln_b + (long)l * HIDN,
                               gate_w + (long)l * 2 * HIDN, gate_b + l,
                               hn + (long)l * LAYER, (int)ROWS);
        }
        gemo(hn + 3L * LAYER, head_w, head_b, nullptr, y,
             BSZN, OUTN, HIDN, OUTN, 0, 0, 0, BIGC, 0);
        return;
    }

    // ---------- split-bf16 MFMA path ----------
    struct CW { u16* hi; u16* lo; };
    u16* wp = (u16*)(xbuf + (long)BSZN * HIDN);
    auto alloc = [&](long rows) { CW cc{wp, wp + rows * 512}; wp += rows * 1024; return cc; };
    CW cWih00 = alloc(1536);
    CW cWhh00 = alloc(1536);
    CW cWhh0r = alloc(4608);
    CW cWih   = alloc(18432);
    CW cWhh   = alloc(18432);
    CW cInw   = alloc(6144);
    CW cOutw  = alloc(2048);
    CW cHw    = alloc(32000);
    CW cA     = alloc(16384);      // activation scratch (hl / qk-in / obuf)
    CW cX     = alloc(16384);      // activation scratch (x / v-in / head-in)

    auto cvt = [&](const float* X, CW c, long R, const float* idsp, int rpc) {
        int total = (int)(R * 64);
        hipLaunchKernelGGL(cvt_split_k, dim3((total + 255) / 256), dim3(256), 0, stream,
                           X, c.hi, c.lo, idsp, rpc, total);
    };
    auto gemm = [&](CW a, long aOff, CW b, long bOff, const float* bias, float* C,
                    int M, int N, int ldc, long sBc, long sBias, int rpc, int accum) {
        dim3 grid(N / 128, M / 128);
        hipLaunchKernelGGL(gemm_mfma, grid, dim3(256), 0, stream,
                           a.hi + aOff * 512, a.lo + aOff * 512,
                           b.hi + bOff * 512, b.lo + bOff * 512,
                           bias, C, ldc, sBc, sBias, rpc, accum);
    };

    hipLaunchKernelGGL(embed_k, dim3((BSZN * HIDN) / 256), dim3(256), 0, stream,
                       tokens, emb, xbuf, BSZN * HIDN);

    cvt(W_ih_00, cWih00, 1536, nullptr, 1);
    cvt(W_hh_00, cWhh00, 1536, nullptr, 1);
    cvt(W_hh_0r, cWhh0r, 4608, nullptr, 1);
    cvt(W_ih,    cWih,  18432, nullptr, 1);
    cvt(W_hh,    cWhh,  18432, nullptr, 1);
    cvt(in_w,    cInw,   6144, nullptr, 1);
    cvt(out_w,   cOutw,  2048, nullptr, 1);
    cvt(head_w,  cHw,   32000, nullptr, 1);
    cvt(xbuf,    cX,     4096, nullptr, 1);

    for (int l = 0; l < LNUM; ++l) {
        const float* hl = h_in + (long)l * LAYER;
        cvt(hl, cA, ROWS, nullptr, 1);
        if (l == 0) {
            gemm(cX, 0, cWih00, 0, b_ih_00, S, BSZN, H3, H3, 0, 0, BIGC, 0);
            int total = (CNUM - 1) * BSZN * H3;
            hipLaunchKernelGGL(fill_bias_k, dim3((total + 255) / 256), dim3(256), 0, stream,
                               S + (long)BSZN * H3, b_ih_0r, H3, (long)H3, BSZN, total);
            gemm(cA, 0, cWhh00, 0, b_hh_00, S, BSZN, 1024, H3, 0, 0, BIGC, 1);
            gemm(cA, 0, cWhh00, 1024, b_hh_00 + 1024, Hn, BSZN, HIDN, HIDN, 0, 0, BIGC, 0);
            gemm(cA, BSZN, cWhh0r, 0, b_hh_0r, S + (long)BSZN * H3,
                 (CNUM - 1) * BSZN, 1024, H3, (long)H3 * HIDN, (long)H3, BSZN, 1);
            gemm(cA, BSZN, cWhh0r, 1024, b_hh_0r + 1024, Hn + (long)BSZN * HIDN,
                 (CNUM - 1) * BSZN, HIDN, HIDN, (long)H3 * HIDN, (long)H3, BSZN, 0);
        } else {
            cvt(hn + (long)(l - 1) * LAYER, cX, ROWS, nullptr, 1);
            long wo = (long)(l - 1) * CNUM * H3;   // 6144-row offset into cWih/cWhh
            gemm(cX, 0, cWih, wo, b_ih + wo, S, (int)ROWS, H3, H3,
                 (long)H3 * HIDN, (long)H3, BSZN, 0);
            gemm(cA, 0, cWhh, wo, b_hh + wo, S, (int)ROWS, 1024, H3,
                 (long)H3 * HIDN, (long)H3, BSZN, 1);
            gemm(cA, 0, cWhh, wo + 1024, b_hh + wo + 1024, Hn, (int)ROWS, HIDN, HIDN,
                 (long)H3 * HIDN, (long)H3, BSZN, 0);
        }
        hipLaunchKernelGGL(gru_gates_k, dim3((ROWS * HIDN) / 256), dim3(256), 0, stream,
                           S, Hn, hl, hln, (int)(ROWS * HIDN));
        // qk projection: input = hln + ids[l][c], output aliases S
        cvt(hln, cA, ROWS, ids + (long)l * CNUM * HIDN, BSZN);
        gemm(cA, 0, cInw, (long)l * H3, in_b + (long)l * H3, qk,
             (int)ROWS, 1024, 1024, 0, 0, BIGC, 0);
        // v projection
        cvt(hln, cX, ROWS, nullptr, 1);
        gemm(cX, 0, cInw, (long)l * H3 + 1024, in_b + (long)l * H3 + 1024, vbuf,
             (int)ROWS, HIDN, HIDN, 0, 0, BIGC, 0);
        hipLaunchKernelGGL(attn_k, dim3((BSZN * NHEAD * 64) / 256), dim3(256), 0, stream,
                           qk, vbuf, obuf);
        // out projection
        cvt(obuf, cA, ROWS, nullptr, 1);
        gemm(cA, 0, cOutw, (long)l * HIDN, out_b + (long)l * HIDN, mpre,
             (int)ROWS, HIDN, HIDN, 0, 0, BIGC, 0);
        hipLaunchKernelGGL(ln_gate_k, dim3((ROWS * 64) / 256), dim3(256), 0, stream,
                           mpre, hln, ln_g + (long)l * HIDN, ln_b + (long)l * HIDN,
                           gate_w + (long)l * 2 * HIDN, gate_b + l,
                           hn + (long)l * LAYER, (int)ROWS);
    }

    // head
    cvt(hn + 3L * LAYER, cX, BSZN, nullptr, 1);
    gemm(cX, 0, cHw, 0, head_b, y, BSZN, OUTN, OUTN, 0, 0, BIGC, 0);
}